// Round 5
// baseline (222.117 us; speedup 1.0000x reference)
//
#include <hip/hip_runtime.h>
#include <math.h>

// QCCNN fused kernel for MI355X (gfx950) — Round 5 (= R3/R4 resubmit; both
// prior rounds hit GPU-acquisition timeouts and never ran).
// Thread = (image, quantum-kernel k) in phase A (4 threads/image, 9 patches
// each: extract->normalize->simulate->3 feats to LDS), then phase B: fc1 with
// 2 images/lane and 8 outputs/lane (w1 read from global/L1 as float4 along f),
// fc2 partials reduced via LDS. No __shfl.
//
// R2 failure mode fixed here: VGPR=256 + spilling (57MB scratch writes) +
// 2-waves/SIMD grid ceiling -> 11% occupancy, latency-bound.

#define QC_EPS 1e-12f
#define PADF 109   // s_feats row stride: 109 % 32 = 13, gcd(13,32)=1 -> conflict-free scalar reads

__device__ __forceinline__ float leakyf(float v) { return v >= 0.0f ? v : 0.1f * v; }

__global__ __launch_bounds__(256, 4) void qccnn_fused(
    const float* __restrict__ x,     // (B,1,8,8)
    const float* __restrict__ qw,    // (4,4,3)
    const float* __restrict__ w1,    // (32,108)
    const float* __restrict__ b1,    // (32,)
    const float* __restrict__ w2,    // (3,32)
    const float* __restrict__ b2,    // (3,)
    float* __restrict__ out,         // (B,3)
    int Bsz)
{
    __shared__ float s_feats[64][PADF];  // 27.9 KB: per-image 108 leaky'd features
    __shared__ float s_qm[4][4][9];      // padded row 9 -> k-varying reads conflict-free
    __shared__ float s_red[128][6];      // fc2 partials: [pair*4+part][img0:3 | img1:3]

    const int tid = threadIdx.x;

    // ---- rotation-matrix setup (16 threads) ----
    if (tid < 16) {
        const int k = tid >> 2, q = tid & 3;
        const float phi = qw[(k * 4 + q) * 3 + 0];
        const float th  = qw[(k * 4 + q) * 3 + 1];
        const float om  = qw[(k * 4 + q) * 3 + 2];
        float c, s, ca, sa, cb, sb;
        sincosf(0.5f * th, &s, &c);
        sincosf(0.5f * (phi + om), &sa, &ca);
        sincosf(0.5f * (phi - om), &sb, &cb);
        float* M = &s_qm[k][q][0];
        // m00 = exp(-i(phi+om)/2)*c ; m01 = -exp(+i(phi-om)/2)*s
        // m10 = exp(-i(phi-om)/2)*s ; m11 = exp(+i(phi+om)/2)*c
        M[0] =  ca * c;  M[1] = -sa * c;
        M[2] = -cb * s;  M[3] = -sb * s;
        M[4] =  cb * s;  M[5] = -sb * s;
        M[6] =  ca * c;  M[7] =  sa * c;
    }
    __syncthreads();

    // =====================  PHASE A: quantum features  =====================
    {
        const int img_l = tid >> 2;          // 0..63
        const int k     = tid & 3;           // quantum kernel owned by this thread
        const int b     = blockIdx.x * 64 + img_l;
        const bool valid = (b < Bsz);

        // preload this kernel's 4 rotation matrices into registers (static idx only)
        float M[4][8];
#pragma unroll
        for (int q = 0; q < 4; ++q)
#pragma unroll
            for (int e = 0; e < 8; ++e) M[q][e] = s_qm[k][q][e];

        // CNOT chain (0,1)(1,2)(2,3)(3,0) folded into measurement indexing
        constexpr int PERM[16] = {0, 13, 3, 14, 6, 11, 5, 8, 12, 1, 15, 2, 10, 7, 9, 4};

        const float* xb = x + (size_t)b * 64;
        int pi = 0, pj = 0;
#pragma unroll 1
        for (int pt = 0; pt < 9; ++pt) {
            // ---- extract + normalize 4x4 patch ----
            float p[16];
            if (valid) {
                const float* pr = xb + pi * 16 + pj * 2;
#pragma unroll
                for (int r = 0; r < 4; ++r) {
                    const float2 lo = *reinterpret_cast<const float2*>(pr + r * 8);
                    const float2 hi = *reinterpret_cast<const float2*>(pr + r * 8 + 2);
                    p[r * 4 + 0] = lo.x; p[r * 4 + 1] = lo.y;
                    p[r * 4 + 2] = hi.x; p[r * 4 + 3] = hi.y;
                }
            } else {
#pragma unroll
                for (int l = 0; l < 16; ++l) p[l] = 0.0f;
            }
            float ss = 0.0f;
#pragma unroll
            for (int l = 0; l < 16; ++l) ss += p[l] * p[l];
            const float inv = 1.0f / (sqrtf(ss) + QC_EPS);
#pragma unroll
            for (int l = 0; l < 16; ++l) p[l] *= inv;

            // ---- simulate kernel k ----
            float sr[16], si[16];
            {   // gate on qubit 3 (mask 1), real input
                const float m00r = M[3][0], m00i = M[3][1], m01r = M[3][2], m01i = M[3][3];
                const float m10r = M[3][4], m10i = M[3][5], m11r = M[3][6], m11i = M[3][7];
#pragma unroll
                for (int t = 0; t < 8; ++t) {
                    const float a0 = p[2 * t], a1 = p[2 * t + 1];
                    sr[2 * t]     = m00r * a0 + m01r * a1;
                    si[2 * t]     = m00i * a0 + m01i * a1;
                    sr[2 * t + 1] = m10r * a0 + m11r * a1;
                    si[2 * t + 1] = m10i * a0 + m11i * a1;
                }
            }
#pragma unroll
            for (int g = 0; g < 3; ++g) {   // gates on qubits 2,1,0 (masks 2,4,8)
                const int qq = (g == 0) ? 2 : ((g == 1) ? 1 : 0);
                const int m  = (g == 0) ? 2 : ((g == 1) ? 4 : 8);
                const float m00r = M[qq][0], m00i = M[qq][1], m01r = M[qq][2], m01i = M[qq][3];
                const float m10r = M[qq][4], m10i = M[qq][5], m11r = M[qq][6], m11i = M[qq][7];
#pragma unroll
                for (int i0 = 0; i0 < 16; ++i0) {
                    if (i0 & m) continue;
                    const int i1 = i0 | m;
                    const float t0r = sr[i0], t0i = si[i0];
                    const float t1r = sr[i1], t1i = si[i1];
                    sr[i0] = m00r * t0r - m00i * t0i + m01r * t1r - m01i * t1i;
                    si[i0] = m00r * t0i + m00i * t0r + m01r * t1i + m01i * t1r;
                    sr[i1] = m10r * t0r - m10i * t0i + m11r * t1r - m11i * t1i;
                    si[i1] = m10r * t0i + m10i * t0r + m11r * t1i + m11i * t1r;
                }
            }

            // ---- measurement (CNOT perm folded in) ----
            float abr = 0.0f, abi = 0.0f, zz = 0.0f;
#pragma unroll
            for (int jj = 0; jj < 8; ++jj) {
                const int ia = PERM[jj], ib = PERM[8 + jj];
                const float ar = sr[ia], ai = si[ia];
                const float br = sr[ib], bi = si[ib];
                abr += ar * br + ai * bi;
                abi += ar * bi - ai * br;
                zz  += (ar * ar + ai * ai) - (br * br + bi * bi);
            }

            // ---- leaky + store 3 features: f = k*27 + comp*9 + pt ----
            {
                const float f0 = leakyf(2.0f * abr);
                const float f1 = leakyf(2.0f * abi);
                const float f2 = leakyf(zz);
                float* row = &s_feats[img_l][k * 27 + pt];
                row[0]  = f0;
                row[9]  = f1;
                row[18] = f2;
            }

            if (++pj == 3) { pj = 0; ++pi; }
        }
    }
    __syncthreads();

    // =====================  PHASE B: fc1 (+ fc2 partials)  =====================
    if (tid < 128) {
        const int part   = tid & 3;          // owns outputs o = part*8 .. part*8+7
        const int pairid = tid >> 2;         // 0..31 -> images {2p, 2p+1}
        const int i0 = pairid * 2, i1 = i0 + 1;
        const int obase = part * 8;

        float h0[8], h1[8];
#pragma unroll
        for (int j = 0; j < 8; ++j) { h0[j] = 0.0f; h1[j] = 0.0f; }

#pragma unroll 1
        for (int f4 = 0; f4 < 27; ++f4) {
            const int f = f4 * 4;
            const float a0 = s_feats[i0][f + 0], a1 = s_feats[i0][f + 1];
            const float a2 = s_feats[i0][f + 2], a3 = s_feats[i0][f + 3];
            const float c0 = s_feats[i1][f + 0], c1 = s_feats[i1][f + 1];
            const float c2 = s_feats[i1][f + 2], c3 = s_feats[i1][f + 3];
#pragma unroll
            for (int j = 0; j < 8; ++j) {
                const float4 wv = *reinterpret_cast<const float4*>(&w1[(obase + j) * 108 + f]);
                h0[j] += wv.x * a0 + wv.y * a1 + wv.z * a2 + wv.w * a3;
                h1[j] += wv.x * c0 + wv.y * c1 + wv.z * c2 + wv.w * c3;
            }
        }

        // fc2 partials over this lane's 8 outputs
        float o00 = 0.0f, o01 = 0.0f, o02 = 0.0f;
        float o10 = 0.0f, o11 = 0.0f, o12 = 0.0f;
#pragma unroll
        for (int j = 0; j < 8; ++j) {
            const float bb  = b1[obase + j];
            const float hv0 = leakyf(h0[j] + bb);
            const float hv1 = leakyf(h1[j] + bb);
            const float w20 = w2[obase + j];
            const float w21 = w2[32 + obase + j];
            const float w22 = w2[64 + obase + j];
            o00 += w20 * hv0; o01 += w21 * hv0; o02 += w22 * hv0;
            o10 += w20 * hv1; o11 += w21 * hv1; o12 += w22 * hv1;
        }
        s_red[tid][0] = o00; s_red[tid][1] = o01; s_red[tid][2] = o02;
        s_red[tid][3] = o10; s_red[tid][4] = o11; s_red[tid][5] = o12;
    }
    __syncthreads();

    // =====================  final reduce + write (64 threads)  =====================
    if (tid < 64) {
        const int pair = tid >> 1, sub = tid & 1;
        const int bo = blockIdx.x * 64 + tid;
        if (bo < Bsz) {
            float r0 = b2[0], r1 = b2[1], r2 = b2[2];
#pragma unroll
            for (int part = 0; part < 4; ++part) {
                const float* rr = s_red[pair * 4 + part];
                r0 += rr[sub * 3 + 0];
                r1 += rr[sub * 3 + 1];
                r2 += rr[sub * 3 + 2];
            }
            out[(size_t)bo * 3 + 0] = r0;
            out[(size_t)bo * 3 + 1] = r1;
            out[(size_t)bo * 3 + 2] = r2;
        }
    }
}

extern "C" void kernel_launch(void* const* d_in, const int* in_sizes, int n_in,
                              void* d_out, int out_size, void* d_ws, size_t ws_size,
                              hipStream_t stream) {
    (void)n_in; (void)out_size; (void)d_ws; (void)ws_size;
    const float* x  = (const float*)d_in[0];
    const float* qw = (const float*)d_in[1];
    const float* w1 = (const float*)d_in[2];
    const float* b1 = (const float*)d_in[3];
    const float* w2 = (const float*)d_in[4];
    const float* b2 = (const float*)d_in[5];
    float* out = (float*)d_out;

    const int Bsz = in_sizes[0] / 64;            // x is (B,1,8,8)
    const int blocks = (Bsz + 63) / 64;          // 64 images per block

    qccnn_fused<<<blocks, 256, 0, stream>>>(x, qw, w1, b1, w2, b2, out, Bsz);
}

// Round 7
// 158.368 us; speedup vs baseline: 1.4025x; 1.4025x over previous
//
#include <hip/hip_runtime.h>
#include <math.h>

// QCCNN fused kernel for MI355X (gfx950) — Round 7 (= R6 resubmit; R6 hit a
// GPU-acquisition timeout and never ran). Single-phase, spill-free.
// R5 post-mortem: __launch_bounds__(256,4) forced VGPR=64 -> scratch spill
// (WRITE_SIZE 34MB vs 1.6MB output) -> same 163us as R2. This round:
//   - no min-waves clamp (let VGPR land ~110, NO spill)
//   - thread = (image, quantum-kernel k); fc1 partials h[32] kept in REGISTERS,
//     accumulated per-feature as features are produced (phase B deleted)
//   - w1^T staged in LDS [108][36] (pad -> 4 k-threads hit disjoint bank quads)
//   - h reduced across the 4 k-threads via two padded LDS buffers, 2 barriers
//   - lane k=0 does bias+leaky+fc2 and writes out[b*3..]

#define QC_EPS 1e-12f

__device__ __forceinline__ float leakyf(float v) { return v >= 0.0f ? v : 0.1f * v; }

__global__ __launch_bounds__(256) void qccnn_fused(
    const float* __restrict__ x,     // (B,1,8,8)
    const float* __restrict__ qw,    // (4,4,3)
    const float* __restrict__ w1,    // (32,108)
    const float* __restrict__ b1,    // (32,)
    const float* __restrict__ w2,    // (3,32)
    const float* __restrict__ b2,    // (3,)
    float* __restrict__ out,         // (B,3)
    int Bsz)
{
    __shared__ float s_w1t[108][36]; // 15.2 KB; row stride 144B (16B-aligned);
                                     // banks for b128 @ f,f+27,f+54,f+81: 4f+{0,12,24,4} -> disjoint quads
    __shared__ float s_qm[4][4][9];  // k-stride 36 floats == 4 mod 32 -> 4 ks on distinct banks
    __shared__ float s_hA[64][33];   // 8.4 KB; pad 33 -> (img+o)%32 conflict-free
    __shared__ float s_hB[64][33];   // 8.4 KB

    const int tid = threadIdx.x;

    // ---- stage w1^T: s_w1t[f][o] = w1[o*108+f] ----
    for (int idx = tid; idx < 32 * 108; idx += 256) {
        const int o = idx / 108, f = idx % 108;
        s_w1t[f][o] = w1[idx];
    }
    // ---- rotation matrices ----
    if (tid < 16) {
        const int k = tid >> 2, q = tid & 3;
        const float phi = qw[(k * 4 + q) * 3 + 0];
        const float th  = qw[(k * 4 + q) * 3 + 1];
        const float om  = qw[(k * 4 + q) * 3 + 2];
        float c, s, ca, sa, cb, sb;
        sincosf(0.5f * th, &s, &c);
        sincosf(0.5f * (phi + om), &sa, &ca);
        sincosf(0.5f * (phi - om), &sb, &cb);
        float* M = &s_qm[k][q][0];
        // m00 = exp(-i(phi+om)/2)*c ; m01 = -exp(+i(phi-om)/2)*s
        // m10 = exp(-i(phi-om)/2)*s ; m11 = exp(+i(phi+om)/2)*c
        M[0] =  ca * c;  M[1] = -sa * c;
        M[2] = -cb * s;  M[3] = -sb * s;
        M[4] =  cb * s;  M[5] = -sb * s;
        M[6] =  ca * c;  M[7] =  sa * c;
    }
    __syncthreads();

    const int img_l = tid >> 2;          // 0..63
    const int k     = tid & 3;           // this thread's quantum kernel
    const int b     = blockIdx.x * 64 + img_l;
    const bool valid = (b < Bsz);
    const float* xb = x + (size_t)b * 64;

    float h[32];                         // fc1 partial, register-resident
#pragma unroll
    for (int o = 0; o < 32; ++o) h[o] = 0.0f;

    // CNOT chain (0,1)(1,2)(2,3)(3,0) folded into measurement indexing
    constexpr int PERM[16] = {0, 13, 3, 14, 6, 11, 5, 8, 12, 1, 15, 2, 10, 7, 9, 4};

    int pi = 0, pj = 0;
#pragma unroll 1
    for (int pt = 0; pt < 9; ++pt) {
        // ---- extract + normalize 4x4 patch (global; L1-hit after 1st patch) ----
        float p[16];
        if (valid) {
            const float* pr = xb + pi * 16 + pj * 2;
#pragma unroll
            for (int r = 0; r < 4; ++r) {
                const float2 lo = *reinterpret_cast<const float2*>(pr + r * 8);
                const float2 hi = *reinterpret_cast<const float2*>(pr + r * 8 + 2);
                p[r * 4 + 0] = lo.x; p[r * 4 + 1] = lo.y;
                p[r * 4 + 2] = hi.x; p[r * 4 + 3] = hi.y;
            }
        } else {
#pragma unroll
            for (int l = 0; l < 16; ++l) p[l] = 0.0f;
        }
        float ss = 0.0f;
#pragma unroll
        for (int l = 0; l < 16; ++l) ss += p[l] * p[l];
        const float inv = 1.0f / (sqrtf(ss) + QC_EPS);
#pragma unroll
        for (int l = 0; l < 16; ++l) p[l] *= inv;

        // ---- simulate kernel k (matrices re-read per stage: 8 live regs) ----
        float sr[16], si[16];
        {   // gate on qubit 3 (mask 1), real input
            const float* M = &s_qm[k][3][0];
            const float m00r = M[0], m00i = M[1], m01r = M[2], m01i = M[3];
            const float m10r = M[4], m10i = M[5], m11r = M[6], m11i = M[7];
#pragma unroll
            for (int t = 0; t < 8; ++t) {
                const float a0 = p[2 * t], a1 = p[2 * t + 1];
                sr[2 * t]     = m00r * a0 + m01r * a1;
                si[2 * t]     = m00i * a0 + m01i * a1;
                sr[2 * t + 1] = m10r * a0 + m11r * a1;
                si[2 * t + 1] = m10i * a0 + m11i * a1;
            }
        }
#pragma unroll
        for (int g = 0; g < 3; ++g) {   // gates on qubits 2,1,0 (masks 2,4,8)
            const int qq = (g == 0) ? 2 : ((g == 1) ? 1 : 0);
            const int m  = (g == 0) ? 2 : ((g == 1) ? 4 : 8);
            const float* M = &s_qm[k][qq][0];
            const float m00r = M[0], m00i = M[1], m01r = M[2], m01i = M[3];
            const float m10r = M[4], m10i = M[5], m11r = M[6], m11i = M[7];
#pragma unroll
            for (int i0 = 0; i0 < 16; ++i0) {
                if (i0 & m) continue;
                const int i1 = i0 | m;
                const float t0r = sr[i0], t0i = si[i0];
                const float t1r = sr[i1], t1i = si[i1];
                sr[i0] = m00r * t0r - m00i * t0i + m01r * t1r - m01i * t1i;
                si[i0] = m00r * t0i + m00i * t0r + m01r * t1i + m01i * t1r;
                sr[i1] = m10r * t0r - m10i * t0i + m11r * t1r - m11i * t1i;
                si[i1] = m10r * t0i + m10i * t0r + m11r * t1i + m11i * t1r;
            }
        }

        // ---- measurement (CNOT perm folded in) ----
        float abr = 0.0f, abi = 0.0f, zz = 0.0f;
#pragma unroll
        for (int jj = 0; jj < 8; ++jj) {
            const int ia = PERM[jj], ib = PERM[8 + jj];
            const float ar = sr[ia], ai = si[ia];
            const float br = sr[ib], bi = si[ib];
            abr += ar * br + ai * bi;
            abi += ar * bi - ai * br;
            zz  += (ar * ar + ai * ai) - (br * br + bi * bi);
        }

        // ---- leaky + fc1 accumulate into register h[32] ----
        // feature index f = k*27 + comp*9 + pt
        {
            const float f0 = leakyf(2.0f * abr);
            const float f1 = leakyf(2.0f * abi);
            const float f2 = leakyf(zz);
            const int fb = k * 27 + pt;
#pragma unroll
            for (int comp = 0; comp < 3; ++comp) {
                const float lf = (comp == 0) ? f0 : ((comp == 1) ? f1 : f2);
                const float* wrow = &s_w1t[fb + comp * 9][0];
#pragma unroll
                for (int o4 = 0; o4 < 8; ++o4) {
                    const float4 wv = *reinterpret_cast<const float4*>(&wrow[o4 * 4]);
                    h[o4 * 4 + 0] += wv.x * lf;
                    h[o4 * 4 + 1] += wv.y * lf;
                    h[o4 * 4 + 2] += wv.z * lf;
                    h[o4 * 4 + 3] += wv.w * lf;
                }
            }
        }

        if (++pj == 3) { pj = 0; ++pi; }
    }

    // ---- reduce h across the 4 k-threads of each image (2 barriers) ----
    if (k == 2) {
#pragma unroll
        for (int o = 0; o < 32; ++o) s_hA[img_l][o] = h[o];
    } else if (k == 3) {
#pragma unroll
        for (int o = 0; o < 32; ++o) s_hB[img_l][o] = h[o];
    }
    __syncthreads();
    if (k == 0) {
#pragma unroll
        for (int o = 0; o < 32; ++o) h[o] += s_hA[img_l][o];
    } else if (k == 1) {
        // read-modify-write own buffer: no cross-thread hazard
#pragma unroll
        for (int o = 0; o < 32; ++o) s_hB[img_l][o] += h[o];
    }
    __syncthreads();

    // ---- lane k=0: finish fc1, fc2, write ----
    if (k == 0 && valid) {
        float o0 = b2[0], o1 = b2[1], o2 = b2[2];
#pragma unroll
        for (int o = 0; o < 32; ++o) {
            const float hv = leakyf(h[o] + s_hB[img_l][o] + b1[o]);
            o0 += w2[o] * hv;
            o1 += w2[32 + o] * hv;
            o2 += w2[64 + o] * hv;
        }
        float* ob = out + (size_t)b * 3;
        ob[0] = o0; ob[1] = o1; ob[2] = o2;
    }
}

extern "C" void kernel_launch(void* const* d_in, const int* in_sizes, int n_in,
                              void* d_out, int out_size, void* d_ws, size_t ws_size,
                              hipStream_t stream) {
    (void)n_in; (void)out_size; (void)d_ws; (void)ws_size;
    const float* x  = (const float*)d_in[0];
    const float* qw = (const float*)d_in[1];
    const float* w1 = (const float*)d_in[2];
    const float* b1 = (const float*)d_in[3];
    const float* w2 = (const float*)d_in[4];
    const float* b2 = (const float*)d_in[5];
    float* out = (float*)d_out;

    const int Bsz = in_sizes[0] / 64;            // x is (B,1,8,8)
    const int blocks = (Bsz + 63) / 64;          // 64 images per block

    qccnn_fused<<<blocks, 256, 0, stream>>>(x, qw, w1, b1, w2, b2, out, Bsz);
}

// Round 9
// 155.252 us; speedup vs baseline: 1.4307x; 1.0201x over previous
//
#include <hip/hip_runtime.h>
#include <math.h>

// QCCNN fused kernel for MI355X (gfx950) — Round 9 (= R8 resubmit; R8 hit a
// GPU-acquisition timeout and never ran).
// Delta vs R7 (101us, occ 20%, VALUBusy 63%): replace the LDS-based h[32]
// reduction (s_hA/s_hB = 16.9KB + 2 barriers) with a 2-step __shfl_xor
// butterfly across the 4 k-lanes of each image (lanes 4i..4i+3 of one wave).
// LDS 33.3KB -> 16.1KB: block cap 4 -> 9 per CU (VGPR then caps ~5 waves/SIMD).
// Everything else identical to R7.

#define QC_EPS 1e-12f

__device__ __forceinline__ float leakyf(float v) { return v >= 0.0f ? v : 0.1f * v; }

__global__ __launch_bounds__(256) void qccnn_fused(
    const float* __restrict__ x,     // (B,1,8,8)
    const float* __restrict__ qw,    // (4,4,3)
    const float* __restrict__ w1,    // (32,108)
    const float* __restrict__ b1,    // (32,)
    const float* __restrict__ w2,    // (3,32)
    const float* __restrict__ b2,    // (3,)
    float* __restrict__ out,         // (B,3)
    int Bsz)
{
    __shared__ float s_w1t[108][36]; // 15.2 KB; row stride 144B (16B-aligned);
                                     // banks for b128 @ f,f+27,f+54,f+81: 4f+{0,12,24,4} -> disjoint quads
    __shared__ float s_qm[4][4][9];  // k-stride 36 floats == 4 mod 32 -> 4 ks on distinct banks

    const int tid = threadIdx.x;

    // ---- stage w1^T: s_w1t[f][o] = w1[o*108+f] ----
    for (int idx = tid; idx < 32 * 108; idx += 256) {
        const int o = idx / 108, f = idx % 108;
        s_w1t[f][o] = w1[idx];
    }
    // ---- rotation matrices ----
    if (tid < 16) {
        const int k = tid >> 2, q = tid & 3;
        const float phi = qw[(k * 4 + q) * 3 + 0];
        const float th  = qw[(k * 4 + q) * 3 + 1];
        const float om  = qw[(k * 4 + q) * 3 + 2];
        float c, s, ca, sa, cb, sb;
        sincosf(0.5f * th, &s, &c);
        sincosf(0.5f * (phi + om), &sa, &ca);
        sincosf(0.5f * (phi - om), &sb, &cb);
        float* M = &s_qm[k][q][0];
        // m00 = exp(-i(phi+om)/2)*c ; m01 = -exp(+i(phi-om)/2)*s
        // m10 = exp(-i(phi-om)/2)*s ; m11 = exp(+i(phi+om)/2)*c
        M[0] =  ca * c;  M[1] = -sa * c;
        M[2] = -cb * s;  M[3] = -sb * s;
        M[4] =  cb * s;  M[5] = -sb * s;
        M[6] =  ca * c;  M[7] =  sa * c;
    }
    __syncthreads();

    const int img_l = tid >> 2;          // 0..63
    const int k     = tid & 3;           // this thread's quantum kernel
    const int b     = blockIdx.x * 64 + img_l;
    const bool valid = (b < Bsz);
    const float* xb = x + (size_t)b * 64;

    float h[32];                         // fc1 partial, register-resident
#pragma unroll
    for (int o = 0; o < 32; ++o) h[o] = 0.0f;

    // CNOT chain (0,1)(1,2)(2,3)(3,0) folded into measurement indexing
    constexpr int PERM[16] = {0, 13, 3, 14, 6, 11, 5, 8, 12, 1, 15, 2, 10, 7, 9, 4};

    int pi = 0, pj = 0;
#pragma unroll 1
    for (int pt = 0; pt < 9; ++pt) {
        // ---- extract + normalize 4x4 patch (global; L1-hit after 1st patch) ----
        float p[16];
        if (valid) {
            const float* pr = xb + pi * 16 + pj * 2;
#pragma unroll
            for (int r = 0; r < 4; ++r) {
                const float2 lo = *reinterpret_cast<const float2*>(pr + r * 8);
                const float2 hi = *reinterpret_cast<const float2*>(pr + r * 8 + 2);
                p[r * 4 + 0] = lo.x; p[r * 4 + 1] = lo.y;
                p[r * 4 + 2] = hi.x; p[r * 4 + 3] = hi.y;
            }
        } else {
#pragma unroll
            for (int l = 0; l < 16; ++l) p[l] = 0.0f;
        }
        float ss = 0.0f;
#pragma unroll
        for (int l = 0; l < 16; ++l) ss += p[l] * p[l];
        const float inv = 1.0f / (sqrtf(ss) + QC_EPS);
#pragma unroll
        for (int l = 0; l < 16; ++l) p[l] *= inv;

        // ---- simulate kernel k ----
        float sr[16], si[16];
        {   // gate on qubit 3 (mask 1), real input
            const float* M = &s_qm[k][3][0];
            const float m00r = M[0], m00i = M[1], m01r = M[2], m01i = M[3];
            const float m10r = M[4], m10i = M[5], m11r = M[6], m11i = M[7];
#pragma unroll
            for (int t = 0; t < 8; ++t) {
                const float a0 = p[2 * t], a1 = p[2 * t + 1];
                sr[2 * t]     = m00r * a0 + m01r * a1;
                si[2 * t]     = m00i * a0 + m01i * a1;
                sr[2 * t + 1] = m10r * a0 + m11r * a1;
                si[2 * t + 1] = m10i * a0 + m11i * a1;
            }
        }
#pragma unroll
        for (int g = 0; g < 3; ++g) {   // gates on qubits 2,1,0 (masks 2,4,8)
            const int qq = (g == 0) ? 2 : ((g == 1) ? 1 : 0);
            const int m  = (g == 0) ? 2 : ((g == 1) ? 4 : 8);
            const float* M = &s_qm[k][qq][0];
            const float m00r = M[0], m00i = M[1], m01r = M[2], m01i = M[3];
            const float m10r = M[4], m10i = M[5], m11r = M[6], m11i = M[7];
#pragma unroll
            for (int i0 = 0; i0 < 16; ++i0) {
                if (i0 & m) continue;
                const int i1 = i0 | m;
                const float t0r = sr[i0], t0i = si[i0];
                const float t1r = sr[i1], t1i = si[i1];
                sr[i0] = m00r * t0r - m00i * t0i + m01r * t1r - m01i * t1i;
                si[i0] = m00r * t0i + m00i * t0r + m01r * t1i + m01i * t1r;
                sr[i1] = m10r * t0r - m10i * t0i + m11r * t1r - m11i * t1i;
                si[i1] = m10r * t0i + m10i * t0r + m11r * t1i + m11i * t1r;
            }
        }

        // ---- measurement (CNOT perm folded in) ----
        float abr = 0.0f, abi = 0.0f, zz = 0.0f;
#pragma unroll
        for (int jj = 0; jj < 8; ++jj) {
            const int ia = PERM[jj], ib = PERM[8 + jj];
            const float ar = sr[ia], ai = si[ia];
            const float br = sr[ib], bi = si[ib];
            abr += ar * br + ai * bi;
            abi += ar * bi - ai * br;
            zz  += (ar * ar + ai * ai) - (br * br + bi * bi);
        }

        // ---- leaky + fc1 accumulate into register h[32] ----
        // feature index f = k*27 + comp*9 + pt
        {
            const float f0 = leakyf(2.0f * abr);
            const float f1 = leakyf(2.0f * abi);
            const float f2 = leakyf(zz);
            const int fb = k * 27 + pt;
#pragma unroll
            for (int comp = 0; comp < 3; ++comp) {
                const float lf = (comp == 0) ? f0 : ((comp == 1) ? f1 : f2);
                const float* wrow = &s_w1t[fb + comp * 9][0];
#pragma unroll
                for (int o4 = 0; o4 < 8; ++o4) {
                    const float4 wv = *reinterpret_cast<const float4*>(&wrow[o4 * 4]);
                    h[o4 * 4 + 0] += wv.x * lf;
                    h[o4 * 4 + 1] += wv.y * lf;
                    h[o4 * 4 + 2] += wv.z * lf;
                    h[o4 * 4 + 3] += wv.w * lf;
                }
            }
        }

        if (++pj == 3) { pj = 0; ++pi; }
    }

    // ---- reduce h across the 4 k-lanes of each image (in-wave butterfly) ----
#pragma unroll
    for (int o = 0; o < 32; ++o) {
        h[o] += __shfl_xor(h[o], 1);
        h[o] += __shfl_xor(h[o], 2);
    }

    // ---- lane k=0: finish fc1, fc2, write (b1/w2/b2 from global, L1-hot) ----
    if (k == 0 && valid) {
        float o0 = b2[0], o1 = b2[1], o2 = b2[2];
#pragma unroll
        for (int o = 0; o < 32; ++o) {
            const float hv = leakyf(h[o] + b1[o]);
            o0 += w2[o] * hv;
            o1 += w2[32 + o] * hv;
            o2 += w2[64 + o] * hv;
        }
        float* ob = out + (size_t)b * 3;
        ob[0] = o0; ob[1] = o1; ob[2] = o2;
    }
}

extern "C" void kernel_launch(void* const* d_in, const int* in_sizes, int n_in,
                              void* d_out, int out_size, void* d_ws, size_t ws_size,
                              hipStream_t stream) {
    (void)n_in; (void)out_size; (void)d_ws; (void)ws_size;
    const float* x  = (const float*)d_in[0];
    const float* qw = (const float*)d_in[1];
    const float* w1 = (const float*)d_in[2];
    const float* b1 = (const float*)d_in[3];
    const float* w2 = (const float*)d_in[4];
    const float* b2 = (const float*)d_in[5];
    float* out = (float*)d_out;

    const int Bsz = in_sizes[0] / 64;            // x is (B,1,8,8)
    const int blocks = (Bsz + 63) / 64;          // 64 images per block

    qccnn_fused<<<blocks, 256, 0, stream>>>(x, qw, w1, b1, w2, b2, out, Bsz);
}